// Round 10
// baseline (225.327 us; speedup 1.0000x reference)
//
#include <hip/hip_runtime.h>

#define DDIM   4        // D = 2*K-2
#define CIN    64
#define COUT   128
#define CDIM   256      // CIN*DDIM
#define HH     128
#define WWID   128
#define NN     4
#define KK     9        // K*K
#define OFFC   18       // 2*K*K
#define HW     (HH * WWID)

// ---- LDS layout (floats) ----
// xs: 8 wave-private slices; phase0 3x66=198 @stride 66; phase1 6 rows x 72 cols @ stride 73
#define XS_SLICE  438                       // 6*73
#define XS_TOTAL  (8 * XS_SLICE)            // 3504
#define TL_OFF    XS_TOTAL                  // tl[18][64] = 1152 floats
#define YL_OFF    (TL_OFF + OFFC * 64)      // 4656
#define SMEM_FLOATS (YL_OFF + 8192)         // ylds 64x256 bf16 = 32768 B -> total 51392 B
// part bf16[8][18][64] (18432 B) aliases the ylds region, separated by barriers.

typedef __attribute__((ext_vector_type(8))) short bf16x8;
typedef __attribute__((ext_vector_type(4))) float f32x4;

#define RFL(x) __builtin_amdgcn_readfirstlane(x)

__device__ __forceinline__ unsigned short f2bf(float f) {
  union { float f; unsigned u; } c; c.f = f;
  unsigned u = c.u;
  return (unsigned short)((u + 0x7FFFu + ((u >> 16) & 1u)) >> 16);  // RNE
}
__device__ __forceinline__ float bf2f(unsigned short u) {
  union { unsigned u; float f; } c; c.u = (unsigned)u << 16;
  return c.f;
}

__global__ void convert_wpw(const float* __restrict__ w_pw, unsigned short* __restrict__ wbf) {
  int i = blockIdx.x * 256 + threadIdx.x;
  if (i < COUT * CDIM) wbf[i] = f2bf(w_pw[i]);
}

// ---------------------------------------------------------------------------
// Mega-fused kernel. 512 thr = 8 waves; strip = 64 pixels (one h row).
// == round-8 kernel + ONE change: phase-0 ping-pong prefetch with NAMED
// SCALARS (round 9's array-based version hit rule-#20 scratch spills:
// WRITE_SIZE 33->44 MB, dur 91->205 us). Spill tripwire: WRITE_SIZE must
// stay 32768 KB.
// ---------------------------------------------------------------------------
__global__ __launch_bounds__(512, 2)
void fused_all(const float* __restrict__ x, const float* __restrict__ w_off,
               const float* __restrict__ b_off, const float* __restrict__ w_deform,
               const unsigned short* __restrict__ wbf, float* __restrict__ out) {
  __shared__ float smem[SMEM_FLOATS];

  // chunked XCD swizzle (bijective: 1024 blocks = 8 XCDs x 128)
  const int lin = blockIdx.x + 2 * blockIdx.y + 256 * blockIdx.z;
  const int swz = ((lin & 7) << 7) + (lin >> 3);
  const int n  = swz >> 8;
  const int h  = (swz >> 1) & 127;
  const int w0 = (swz & 1) * 64;

  const int tid = threadIdx.x;
  const int pl = tid & 63;          // pixel within strip (== lane)
  const int cg = tid >> 6;          // wave id
  const int w = w0 + pl;
  const int pix = h * WWID + w;

  const float* xn = x + (size_t)n * CIN * HW;
  float* xsl = smem + cg * XS_SLICE;                       // wave-private slice
  float* tl  = smem + TL_OFF;                              // [18][64]
  unsigned short* pt   = (unsigned short*)(smem + YL_OFF); // partials (bf16) alias
  unsigned short* ylds = (unsigned short*)(smem + YL_OFF); // [64][256] bf16

  // ==== phase 0: offset-conv partials, named-scalar ping-pong prefetch ====
  float ao[OFFC];
#pragma unroll
  for (int o = 0; o < OFFC; ++o) ao[o] = 0.f;

  // staging geometry: 3 rows x 66 cols (rows h-1..h+1, cols w0-1..w0+64)
  // lane pl covers elements pl, pl+64, pl+128, pl+192(first 6 lanes)
  int gA0, gA1, gA2, gA3;           // global offsets (clamped; mask in okm)
  int lA0, lA1, lA2, lA3;           // LDS offsets
  unsigned okm = 0;
  {
#pragma unroll
    for (int k = 0; k < 4; ++k) {
      const int i = pl + k * 64;
      const int tr = i / 66, tc = i - tr * 66;
      const int gy = h - 1 + tr, gx = w0 - 1 + tc;
      const bool ok = (i < 198) && gy >= 0 && gy < HH && gx >= 0 && gx < WWID;
      const int g = ok ? (gy * WWID + gx) : 0;
      const int l = tr * 66 + tc;
      if (k == 0) { gA0 = g; lA0 = l; }
      else if (k == 1) { gA1 = g; lA1 = l; }
      else if (k == 2) { gA2 = g; lA2 = l; }
      else { gA3 = g; lA3 = l; }
      okm |= ok ? (1u << k) : 0u;
    }
  }
  auto p0_load = [&](float& b0, float& b1, float& b2, float& b3, int c) {
    const float* xc = xn + (size_t)c * HW;
    b0 = (okm & 1u) ? xc[gA0] : 0.f;
    b1 = (okm & 2u) ? xc[gA1] : 0.f;
    b2 = (okm & 4u) ? xc[gA2] : 0.f;
    b3 = (okm & 8u) ? xc[gA3] : 0.f;
  };
  auto p0_write = [&](float b0, float b1, float b2, float b3) {
    xsl[lA0] = b0;
    xsl[lA1] = b1;
    xsl[lA2] = b2;
    if (pl < 6) xsl[lA3] = b3;      // 198 - 192 = 6 tail lanes
  };
  auto p0_comp = [&](int c) {
    const float center = xsl[66 + pl + 1];
    float v[KK];
#pragma unroll
    for (int p = 0; p < KK; ++p)
      v[p] = xsl[(p / 3) * 66 + pl + (p % 3)] - center;   // v[4]==0
#pragma unroll
    for (int o = 0; o < OFFC; ++o) {
      const float* wrow = w_off + ((size_t)o * CIN + c) * KK;  // SGPR base
      float a = ao[o];
#pragma unroll
      for (int p = 0; p < KK; ++p) {
        if (p == 4) continue;
        a += wrow[p] * v[p];
      }
      ao[o] = a;
    }
  };

  {
    float A0, A1, A2, A3, B0, B1, B2, B3;
    p0_load(A0, A1, A2, A3, RFL(cg * 8));
#pragma unroll
    for (int c2 = 0; c2 < 8; c2 += 2) {
      p0_write(A0, A1, A2, A3);
      p0_load(B0, B1, B2, B3, RFL(cg * 8 + c2 + 1));
      p0_comp(RFL(cg * 8 + c2));
      p0_write(B0, B1, B2, B3);
      if (c2 < 6) p0_load(A0, A1, A2, A3, RFL(cg * 8 + c2 + 2));
      p0_comp(RFL(cg * 8 + c2 + 1));
    }
  }
#pragma unroll
  for (int o = 0; o < OFFC; ++o) pt[(cg * OFFC + o) * 64 + pl] = f2bf(ao[o]);
  __syncthreads();

  // ==== cross-wave reduce -> tl[18][64] ====
  for (int idx = tid; idx < OFFC * 64; idx += 512) {
    const int o = idx >> 6, px = idx & 63;
    float s = b_off[o];
#pragma unroll
    for (int w8 = 0; w8 < 8; ++w8) s += bf2f(pt[(w8 * OFFC + o) * 64 + px]);
    tl[o * 64 + px] = s;
  }
  __syncthreads();    // fences pt reads before ylds (alias) writes

  // ==== tap precompute; UNCLAMPED window origin (row0,col0) may be <0 ====
  const int row0 = h - 3;
  const int col0 = w0 - 3;
  float c00[KK], c01[KK], c10[KK], c11[KK];   // UNMASKED bilinear products
  int gbase[KK];
  unsigned hotm = 0;
#pragma unroll
  for (int p = 0; p < KK; ++p) {
    const float dy = tl[(2 * p) * 64 + pl];
    const float dx = tl[(2 * p + 1) * 64 + pl];
    const float py  = dy + (float)(h + p / 3 - 1);
    const float pxx = dx + (float)(w + p % 3 - 1);
    const float fy = floorf(py), fx = floorf(pxx);
    const int y0 = (int)fy, x0 = (int)fx;
    const float ay = py - fy, ax = pxx - fx;
    const int ty0 = y0 - row0;            // window row of top corner
    const int tx0 = x0 - col0;            // window col of left corner
    if ((unsigned)ty0 <= 4u && (unsigned)tx0 <= 70u) hotm |= 1u << p;
    gbase[p] = ty0 * 73 + tx0;
    const float by = 1.f - ay, bx = 1.f - ax;
    c00[p] = by * bx;  c01[p] = by * ax;
    c10[p] = ay * bx;  c11[p] = ay * ax;
  }
  const bool hot = (__all((int)(hotm == 0x1FFu)) != 0);

  // ==== staging geometry: 6x72 window (432 elems), zero-fill outside image ====
  int g1[7], l1[7];
  unsigned ok7 = 0;                       // in-image mask
#pragma unroll
  for (int k = 0; k < 7; ++k) {
    const int i = pl + k * 64;
    const int r = i / 72, cl = i - r * 72;
    const int gy = row0 + r, gx = col0 + cl;
    const bool act = (i < 432) && gy >= 0 && gy < HH && gx >= 0 && gx < WWID;
    g1[k] = act ? (gy * WWID + gx) : 0;
    l1[k] = r * 73 + cl;
    if (act) ok7 |= 1u << k;
  }
  auto p1_load = [&](float* b, int c) {
    const float* xc = xn + (size_t)c * HW;
#pragma unroll
    for (int k = 0; k < 7; ++k)
      b[k] = ((ok7 >> k) & 1) ? xc[g1[k]] : 0.f;
  };
  auto p1_write = [&](const float* b) {
#pragma unroll
    for (int k = 0; k < 7; ++k) {
      if (k < 6) xsl[l1[k]] = b[k];
      else if (pl < 48) xsl[l1[6]] = b[6];   // 432 - 384 = 48 tail lanes
    }
  };
  auto store_y = [&](int c, float yd0, float yd1, float yd2, float yd3) {
    const unsigned lo = (unsigned)f2bf(yd0) | ((unsigned)f2bf(yd1) << 16);
    const unsigned hi = (unsigned)f2bf(yd2) | ((unsigned)f2bf(yd3) << 16);
    const int ebase = (((c >> 1) ^ (pl & 7)) << 3) + (c & 1) * 4;  // XOR swizzle
    *reinterpret_cast<uint2*>(&ylds[pl * CDIM + ebase]) = make_uint2(lo, hi);
  };

  // hot: branch-free, fully batched gathers (compiler can hoist all 36+1 reads)
  auto p1_comp_hot = [&](int c) {
    const float xcv = xsl[3 * 73 + pl + 3];      // window cell (h, w)
    float g00[KK], g01[KK], g10[KK], g11[KK];
#pragma unroll
    for (int p = 0; p < KK; ++p) {
      const float* bp = &xsl[gbase[p]];
      g00[p] = bp[0];  g01[p] = bp[1];
      g10[p] = bp[73]; g11[p] = bp[74];
    }
    float yd0 = 0.f, yd1 = 0.f, yd2 = 0.f, yd3 = 0.f;
#pragma unroll
    for (int p = 0; p < KK; ++p) {
      const float samp = c00[p] * g00[p] + c01[p] * g01[p]
                       + c10[p] * g10[p] + c11[p] * g11[p];
      const float s = samp - xcv;
      const float* wdp = w_deform + (size_t)(c * DDIM) * KK + p;  // SGPR base
      yd0 += wdp[0 * KK] * s;
      yd1 += wdp[1 * KK] * s;
      yd2 += wdp[2 * KK] * s;
      yd3 += wdp[3 * KK] * s;
    }
    store_y(c, yd0, yd1, yd2, yd3);
  };

  // cold: exact per-tap path (clipped global gathers, masked coefs)
  auto p1_comp_cold = [&](int c) {
    const float* xc = xn + (size_t)c * HW;
    const float xcv = xc[pix];
    float yd0 = 0.f, yd1 = 0.f, yd2 = 0.f, yd3 = 0.f;
#pragma unroll
    for (int p = 0; p < KK; ++p) {
      float samp;
      if (hotm & (1u << p)) {
        const float* bp = &xsl[gbase[p]];
        samp = c00[p] * bp[0] + c01[p] * bp[1] + c10[p] * bp[73] + c11[p] * bp[74];
      } else {
        const float dy = tl[(2 * p) * 64 + pl];
        const float dx = tl[(2 * p + 1) * 64 + pl];
        const float py  = dy + (float)(h + p / 3 - 1);
        const float pxx = dx + (float)(w + p % 3 - 1);
        const float fy = floorf(py), fx = floorf(pxx);
        const int y0 = (int)fy, x0 = (int)fx;
        const int y1 = y0 + 1,  x1 = x0 + 1;
        const bool vy0 = (y0 >= 0) && (y0 < HH), vy1 = (y1 >= 0) && (y1 < HH);
        const bool vx0 = (x0 >= 0) && (x0 < WWID), vx1 = (x1 >= 0) && (x1 < WWID);
        const int yc0 = min(max(y0, 0), HH - 1),  yc1 = min(max(y1, 0), HH - 1);
        const int xc0 = min(max(x0, 0), WWID - 1), xc1 = min(max(x1, 0), WWID - 1);
        const float m00 = (vy0 && vx0) ? c00[p] : 0.f;
        const float m01 = (vy0 && vx1) ? c01[p] : 0.f;
        const float m10 = (vy1 && vx0) ? c10[p] : 0.f;
        const float m11 = (vy1 && vx1) ? c11[p] : 0.f;
        samp = m00 * xc[yc0 * WWID + xc0] + m01 * xc[yc0 * WWID + xc1]
             + m10 * xc[yc1 * WWID + xc0] + m11 * xc[yc1 * WWID + xc1];
      }
      const float s = samp - xcv;
      const float* wdp = w_deform + (size_t)(c * DDIM) * KK + p;
      yd0 += wdp[0 * KK] * s;
      yd1 += wdp[1 * KK] * s;
      yd2 += wdp[2 * KK] * s;
      yd3 += wdp[3 * KK] * s;
    }
    store_y(c, yd0, yd1, yd2, yd3);
  };

  // ping-pong pipeline: global->reg prefetch of next channel's window
  auto pipeline = [&](auto comp) {
    float qA[7], qB[7];
    p1_load(qA, RFL(cg * 8));
#pragma unroll
    for (int c2 = 0; c2 < 8; c2 += 2) {
      p1_write(qA);
      p1_load(qB, RFL(cg * 8 + c2 + 1));
      comp(RFL(cg * 8 + c2));
      p1_write(qB);
      if (c2 < 6) p1_load(qA, RFL(cg * 8 + c2 + 2));
      comp(RFL(cg * 8 + c2 + 1));
    }
  };
  if (hot) pipeline(p1_comp_hot);
  else     pipeline(p1_comp_cold);
  __syncthreads();

  // ==== phase 2: MFMA pointwise; 8 waves -> 4(M) x 2(N) grid of 32x32 tiles ====
  const int l15 = tid & 15;
  const int kg  = (tid & 63) >> 4;
  const int Mb = (cg >> 1) * 32;
  const int Nb = (cg & 1) * 32;

  f32x4 acc[2][2];
#pragma unroll
  for (int mi = 0; mi < 2; ++mi)
#pragma unroll
    for (int ni = 0; ni < 2; ++ni)
      acc[mi][ni] = (f32x4){0.f, 0.f, 0.f, 0.f};

#pragma unroll
  for (int ks = 0; ks < 8; ++ks) {          // K = 256 in steps of 32
    bf16x8 bfr[2];
#pragma unroll
    for (int ni = 0; ni < 2; ++ni) {
      const int prow = Nb + ni * 16 + l15;
      const int chunk = ks * 4 + kg;
      const int eb = ((chunk ^ (prow & 7)) << 3);
      bfr[ni] = *reinterpret_cast<const bf16x8*>(&ylds[prow * CDIM + eb]);
    }
    bf16x8 afr[2];
#pragma unroll
    for (int mi = 0; mi < 2; ++mi) {
      const int o = Mb + mi * 16 + l15;
      afr[mi] = *reinterpret_cast<const bf16x8*>(wbf + (size_t)o * CDIM + ks * 32 + kg * 8);
    }
#pragma unroll
    for (int mi = 0; mi < 2; ++mi)
#pragma unroll
      for (int ni = 0; ni < 2; ++ni)
        acc[mi][ni] = __builtin_amdgcn_mfma_f32_16x16x32_bf16(afr[mi], bfr[ni], acc[mi][ni], 0, 0, 0);
  }

  // ==== epilogue: C/D layout col=lane&15, row=(lane>>4)*4+reg ====
  float* on = out + (size_t)n * COUT * HW;
#pragma unroll
  for (int mi = 0; mi < 2; ++mi) {
#pragma unroll
    for (int ni = 0; ni < 2; ++ni) {
      const int pcol = h * WWID + w0 + Nb + ni * 16 + l15;
#pragma unroll
      for (int reg = 0; reg < 4; ++reg) {
        const int o = Mb + mi * 16 + kg * 4 + reg;
        on[(size_t)o * HW + pcol] = acc[mi][ni][reg];
      }
    }
  }
}

// ---------------------------------------------------------------------------
extern "C" void kernel_launch(void* const* d_in, const int* in_sizes, int n_in,
                              void* d_out, int out_size, void* d_ws, size_t ws_size,
                              hipStream_t stream) {
  const float* x        = (const float*)d_in[0];
  const float* w_off    = (const float*)d_in[1];
  const float* b_off    = (const float*)d_in[2];
  const float* w_deform = (const float*)d_in[3];
  const float* w_pw     = (const float*)d_in[4];
  float* out = (float*)d_out;
  unsigned short* wbf = (unsigned short*)d_ws;   // 65536 B

  convert_wpw<<<dim3(COUT * CDIM / 256), dim3(256), 0, stream>>>(w_pw, wbf);
  fused_all<<<dim3(WWID / 64, HH, NN), dim3(512), 0, stream>>>(x, w_off, b_off, w_deform, wbf, out);
}

// Round 11
// 196.752 us; speedup vs baseline: 1.1452x; 1.1452x over previous
//
#include <hip/hip_runtime.h>

#define DDIM   4        // D = 2*K-2
#define CIN    64
#define COUT   128
#define CDIM   256      // CIN*DDIM
#define HH     128
#define WWID   128
#define NN     4
#define KK     9        // K*K
#define OFFC   18       // 2*K*K
#define HW     (HH * WWID)

// ---- LDS layout (float units) ----
// xs: 8 wave-private slices of 720 floats:
//   phase0: 3x66 fp32 @ stride 66 (198 floats)
//   phase1: row-pair window float2[5][72] (720 floats) — wpair[r][col]=(win[r],win[r+1])
#define XS_SLICE  720
#define XS_TOTAL  (8 * XS_SLICE)            // 5760
#define TL_OFF    XS_TOTAL                  // tl[18][64] fp32 = 1152 floats
#define YL_OFF    (TL_OFF + OFFC * 64)      // 6912
#define SMEM_FLOATS (YL_OFF + 8192)         // ylds 64x256 bf16 = 32768 B -> total 60416 B
// part bf16[8][18][64] (18432 B) aliases the ylds region, separated by barriers.

typedef __attribute__((ext_vector_type(8))) short bf16x8;
typedef __attribute__((ext_vector_type(4))) float f32x4;

#define RFL(x) __builtin_amdgcn_readfirstlane(x)

__device__ __forceinline__ unsigned short f2bf(float f) {
  union { float f; unsigned u; } c; c.f = f;
  unsigned u = c.u;
  return (unsigned short)((u + 0x7FFFu + ((u >> 16) & 1u)) >> 16);  // RNE
}
__device__ __forceinline__ float bf2f(unsigned short u) {
  union { unsigned u; float f; } c; c.u = (unsigned)u << 16;
  return c.f;
}

__global__ void convert_wpw(const float* __restrict__ w_pw, unsigned short* __restrict__ wbf) {
  int i = blockIdx.x * 256 + threadIdx.x;
  if (i < COUT * CDIM) wbf[i] = f2bf(w_pw[i]);
}

// ---------------------------------------------------------------------------
// Mega-fused kernel. 512 thr = 8 waves; strip = 64 pixels (one h row).
// == round-8 kernel + ONE change: phase-1 window stored as ROW-PAIR float2
// (wpair[r][col] = (win[r][col], win[r+1][col])), so each bilinear tap is
// 2 x ds_read_b64 instead of 4 x ds_read_b32 (gathers 36 -> 18 instrs).
// Phase-0 prefetch permanently abandoned (rounds 9/10: scratch-spill
// signature WRITE_SIZE 33->44 MB both times). Spill tripwire: WRITE_SIZE
// must stay 32768 KB.
// ---------------------------------------------------------------------------
__global__ __launch_bounds__(512, 2)
void fused_all(const float* __restrict__ x, const float* __restrict__ w_off,
               const float* __restrict__ b_off, const float* __restrict__ w_deform,
               const unsigned short* __restrict__ wbf, float* __restrict__ out) {
  __shared__ float smem[SMEM_FLOATS];

  // chunked XCD swizzle (bijective: 1024 blocks = 8 XCDs x 128)
  const int lin = blockIdx.x + 2 * blockIdx.y + 256 * blockIdx.z;
  const int swz = ((lin & 7) << 7) + (lin >> 3);
  const int n  = swz >> 8;
  const int h  = (swz >> 1) & 127;
  const int w0 = (swz & 1) * 64;

  const int tid = threadIdx.x;
  const int pl = tid & 63;          // pixel within strip (== lane)
  const int cg = tid >> 6;          // wave id
  const int w = w0 + pl;
  const int pix = h * WWID + w;

  const float* xn = x + (size_t)n * CIN * HW;
  float* xsl = smem + cg * XS_SLICE;                       // wave-private slice
  float2* wpair = reinterpret_cast<float2*>(xsl);          // phase-1 pair view
  float* tl  = smem + TL_OFF;                              // [18][64]
  unsigned short* pt   = (unsigned short*)(smem + YL_OFF); // partials (bf16) alias
  unsigned short* ylds = (unsigned short*)(smem + YL_OFF); // [64][256] bf16

  // ==== phase 0: offset-conv partials (this wave's 8 channels), simple ====
  float ao[OFFC];
#pragma unroll
  for (int o = 0; o < OFFC; ++o) ao[o] = 0.f;

#pragma unroll 1
  for (int ci = 0; ci < 8; ++ci) {
    const int c = RFL(cg * 8 + ci);
    const float* xc = xn + (size_t)c * HW;
    for (int i = pl; i < 198; i += 64) {
      const int tr = i / 66, tc = i - tr * 66;
      const int gy = h - 1 + tr, gx = w0 - 1 + tc;
      float v = 0.f;
      if (gy >= 0 && gy < HH && gx >= 0 && gx < WWID) v = xc[gy * WWID + gx];
      xsl[tr * 66 + tc] = v;    // wave-private: per-wave LDS ordering suffices
    }
    const float center = xsl[66 + pl + 1];
    float v[KK];
#pragma unroll
    for (int p = 0; p < KK; ++p)
      v[p] = xsl[(p / 3) * 66 + pl + (p % 3)] - center;   // v[4]==0
#pragma unroll
    for (int o = 0; o < OFFC; ++o) {
      const float* wrow = w_off + ((size_t)o * CIN + c) * KK;  // SGPR base
      float a = ao[o];
#pragma unroll
      for (int p = 0; p < KK; ++p) {
        if (p == 4) continue;
        a += wrow[p] * v[p];
      }
      ao[o] = a;
    }
  }
#pragma unroll
  for (int o = 0; o < OFFC; ++o) pt[(cg * OFFC + o) * 64 + pl] = f2bf(ao[o]);
  __syncthreads();

  // ==== cross-wave reduce -> tl[18][64] ====
  for (int idx = tid; idx < OFFC * 64; idx += 512) {
    const int o = idx >> 6, px = idx & 63;
    float s = b_off[o];
#pragma unroll
    for (int w8 = 0; w8 < 8; ++w8) s += bf2f(pt[(w8 * OFFC + o) * 64 + px]);
    tl[o * 64 + px] = s;
  }
  __syncthreads();    // fences pt reads before ylds (alias) writes

  // ==== tap precompute; UNCLAMPED window origin (row0,col0) may be <0 ====
  const int row0 = h - 3;
  const int col0 = w0 - 3;
  float c00[KK], c01[KK], c10[KK], c11[KK];   // UNMASKED bilinear products
  int gbase[KK];                              // float2-unit index: ty0*72+tx0
  unsigned hotm = 0;
#pragma unroll
  for (int p = 0; p < KK; ++p) {
    const float dy = tl[(2 * p) * 64 + pl];
    const float dx = tl[(2 * p + 1) * 64 + pl];
    const float py  = dy + (float)(h + p / 3 - 1);
    const float pxx = dx + (float)(w + p % 3 - 1);
    const float fy = floorf(py), fx = floorf(pxx);
    const int y0 = (int)fy, x0 = (int)fx;
    const float ay = py - fy, ax = pxx - fx;
    const int ty0 = y0 - row0;            // window row of top corner (pair row)
    const int tx0 = x0 - col0;            // window col of left corner
    if ((unsigned)ty0 <= 4u && (unsigned)tx0 <= 70u) hotm |= 1u << p;
    gbase[p] = ty0 * 72 + tx0;
    const float by = 1.f - ay, bx = 1.f - ax;
    c00[p] = by * bx;  c01[p] = by * ax;
    c10[p] = ay * bx;  c11[p] = ay * ax;
  }
  const bool hot = (__all((int)(hotm == 0x1FFu)) != 0);

  // ==== staging geometry: 5x72 PAIR window (360 float2), zero-fill OOB ====
  int gp0[6], gp1[6], lp[6];
  unsigned okA = 0, okB = 0;               // in-image masks for .x / .y
#pragma unroll
  for (int k = 0; k < 6; ++k) {
    const int e = pl + k * 64;
    const int pr = e / 72, col = e - pr * 72;
    const int gy0 = row0 + pr, gy1 = gy0 + 1, gx = col0 + col;
    const bool act = (e < 360);
    const bool okx = act && gy0 >= 0 && gy0 < HH && gx >= 0 && gx < WWID;
    const bool oky = act && gy1 >= 0 && gy1 < HH && gx >= 0 && gx < WWID;
    gp0[k] = okx ? (gy0 * WWID + gx) : 0;
    gp1[k] = oky ? (gy1 * WWID + gx) : 0;
    lp[k]  = pr * 72 + col;                // float2 units
    if (okx) okA |= 1u << k;
    if (oky) okB |= 1u << k;
  }
  auto p1_load = [&](float2* b, int c) {
    const float* xc = xn + (size_t)c * HW;
#pragma unroll
    for (int k = 0; k < 6; ++k) {
      b[k].x = ((okA >> k) & 1) ? xc[gp0[k]] : 0.f;
      b[k].y = ((okB >> k) & 1) ? xc[gp1[k]] : 0.f;
    }
  };
  auto p1_write = [&](const float2* b) {
#pragma unroll
    for (int k = 0; k < 6; ++k) {
      if (k < 5) wpair[lp[k]] = b[k];
      else if (pl < 40) wpair[lp[5]] = b[5];   // 360 - 320 = 40 tail lanes
    }
  };
  auto store_y = [&](int c, float yd0, float yd1, float yd2, float yd3) {
    const unsigned lo = (unsigned)f2bf(yd0) | ((unsigned)f2bf(yd1) << 16);
    const unsigned hi = (unsigned)f2bf(yd2) | ((unsigned)f2bf(yd3) << 16);
    const int ebase = (((c >> 1) ^ (pl & 7)) << 3) + (c & 1) * 4;  // XOR swizzle
    *reinterpret_cast<uint2*>(&ylds[pl * CDIM + ebase]) = make_uint2(lo, hi);
  };

  // hot: branch-free; per tap 2 x ds_read_b64 yields all 4 bilinear corners
  auto p1_comp_hot = [&](int c) {
    const float xcv = wpair[3 * 72 + 3 + pl].x;   // window (row 3 = h, col 3+pl = w)
    float2 ga[KK], gb[KK];
#pragma unroll
    for (int p = 0; p < KK; ++p) {
      ga[p] = wpair[gbase[p]];        // (g00, g10)
      gb[p] = wpair[gbase[p] + 1];    // (g01, g11)
    }
    float yd0 = 0.f, yd1 = 0.f, yd2 = 0.f, yd3 = 0.f;
#pragma unroll
    for (int p = 0; p < KK; ++p) {
      const float samp = c00[p] * ga[p].x + c01[p] * gb[p].x
                       + c10[p] * ga[p].y + c11[p] * gb[p].y;
      const float s = samp - xcv;
      const float* wdp = w_deform + (size_t)(c * DDIM) * KK + p;  // SGPR base
      yd0 += wdp[0 * KK] * s;
      yd1 += wdp[1 * KK] * s;
      yd2 += wdp[2 * KK] * s;
      yd3 += wdp[3 * KK] * s;
    }
    store_y(c, yd0, yd1, yd2, yd3);
  };

  // cold: exact per-tap path (in-window taps via pairs; others global+masked)
  auto p1_comp_cold = [&](int c) {
    const float* xc = xn + (size_t)c * HW;
    const float xcv = xc[pix];
    float yd0 = 0.f, yd1 = 0.f, yd2 = 0.f, yd3 = 0.f;
#pragma unroll
    for (int p = 0; p < KK; ++p) {
      float samp;
      if (hotm & (1u << p)) {
        const float2 ga = wpair[gbase[p]];
        const float2 gb = wpair[gbase[p] + 1];
        samp = c00[p] * ga.x + c01[p] * gb.x + c10[p] * ga.y + c11[p] * gb.y;
      } else {
        const float dy = tl[(2 * p) * 64 + pl];
        const float dx = tl[(2 * p + 1) * 64 + pl];
        const float py  = dy + (float)(h + p / 3 - 1);
        const float pxx = dx + (float)(w + p % 3 - 1);
        const float fy = floorf(py), fx = floorf(pxx);
        const int y0 = (int)fy, x0 = (int)fx;
        const int y1 = y0 + 1,  x1 = x0 + 1;
        const bool vy0 = (y0 >= 0) && (y0 < HH), vy1 = (y1 >= 0) && (y1 < HH);
        const bool vx0 = (x0 >= 0) && (x0 < WWID), vx1 = (x1 >= 0) && (x1 < WWID);
        const int yc0 = min(max(y0, 0), HH - 1),  yc1 = min(max(y1, 0), HH - 1);
        const int xc0 = min(max(x0, 0), WWID - 1), xc1 = min(max(x1, 0), WWID - 1);
        const float m00 = (vy0 && vx0) ? c00[p] : 0.f;
        const float m01 = (vy0 && vx1) ? c01[p] : 0.f;
        const float m10 = (vy1 && vx0) ? c10[p] : 0.f;
        const float m11 = (vy1 && vx1) ? c11[p] : 0.f;
        samp = m00 * xc[yc0 * WWID + xc0] + m01 * xc[yc0 * WWID + xc1]
             + m10 * xc[yc1 * WWID + xc0] + m11 * xc[yc1 * WWID + xc1];
      }
      const float s = samp - xcv;
      const float* wdp = w_deform + (size_t)(c * DDIM) * KK + p;
      yd0 += wdp[0 * KK] * s;
      yd1 += wdp[1 * KK] * s;
      yd2 += wdp[2 * KK] * s;
      yd3 += wdp[3 * KK] * s;
    }
    store_y(c, yd0, yd1, yd2, yd3);
  };

  // ping-pong pipeline: global->reg prefetch of next channel's pair window
  auto pipeline = [&](auto comp) {
    float2 qA[6], qB[6];
    p1_load(qA, RFL(cg * 8));
#pragma unroll
    for (int c2 = 0; c2 < 8; c2 += 2) {
      p1_write(qA);
      p1_load(qB, RFL(cg * 8 + c2 + 1));
      comp(RFL(cg * 8 + c2));
      p1_write(qB);
      if (c2 < 6) p1_load(qA, RFL(cg * 8 + c2 + 2));
      comp(RFL(cg * 8 + c2 + 1));
    }
  };
  if (hot) pipeline(p1_comp_hot);
  else     pipeline(p1_comp_cold);
  __syncthreads();

  // ==== phase 2: MFMA pointwise; 8 waves -> 4(M) x 2(N) grid of 32x32 tiles ====
  const int l15 = tid & 15;
  const int kg  = (tid & 63) >> 4;
  const int Mb = (cg >> 1) * 32;
  const int Nb = (cg & 1) * 32;

  f32x4 acc[2][2];
#pragma unroll
  for (int mi = 0; mi < 2; ++mi)
#pragma unroll
    for (int ni = 0; ni < 2; ++ni)
      acc[mi][ni] = (f32x4){0.f, 0.f, 0.f, 0.f};

#pragma unroll
  for (int ks = 0; ks < 8; ++ks) {          // K = 256 in steps of 32
    bf16x8 bfr[2];
#pragma unroll
    for (int ni = 0; ni < 2; ++ni) {
      const int prow = Nb + ni * 16 + l15;
      const int chunk = ks * 4 + kg;
      const int eb = ((chunk ^ (prow & 7)) << 3);
      bfr[ni] = *reinterpret_cast<const bf16x8*>(&ylds[prow * CDIM + eb]);
    }
    bf16x8 afr[2];
#pragma unroll
    for (int mi = 0; mi < 2; ++mi) {
      const int o = Mb + mi * 16 + l15;
      afr[mi] = *reinterpret_cast<const bf16x8*>(wbf + (size_t)o * CDIM + ks * 32 + kg * 8);
    }
#pragma unroll
    for (int mi = 0; mi < 2; ++mi)
#pragma unroll
      for (int ni = 0; ni < 2; ++ni)
        acc[mi][ni] = __builtin_amdgcn_mfma_f32_16x16x32_bf16(afr[mi], bfr[ni], acc[mi][ni], 0, 0, 0);
  }

  // ==== epilogue: C/D layout col=lane&15, row=(lane>>4)*4+reg ====
  float* on = out + (size_t)n * COUT * HW;
#pragma unroll
  for (int mi = 0; mi < 2; ++mi) {
#pragma unroll
    for (int ni = 0; ni < 2; ++ni) {
      const int pcol = h * WWID + w0 + Nb + ni * 16 + l15;
#pragma unroll
      for (int reg = 0; reg < 4; ++reg) {
        const int o = Mb + mi * 16 + kg * 4 + reg;
        on[(size_t)o * HW + pcol] = acc[mi][ni][reg];
      }
    }
  }
}

// ---------------------------------------------------------------------------
extern "C" void kernel_launch(void* const* d_in, const int* in_sizes, int n_in,
                              void* d_out, int out_size, void* d_ws, size_t ws_size,
                              hipStream_t stream) {
  const float* x        = (const float*)d_in[0];
  const float* w_off    = (const float*)d_in[1];
  const float* b_off    = (const float*)d_in[2];
  const float* w_deform = (const float*)d_in[3];
  const float* w_pw     = (const float*)d_in[4];
  float* out = (float*)d_out;
  unsigned short* wbf = (unsigned short*)d_ws;   // 65536 B

  convert_wpw<<<dim3(COUT * CDIM / 256), dim3(256), 0, stream>>>(w_pw, wbf);
  fused_all<<<dim3(WWID / 64, HH, NN), dim3(512), 0, stream>>>(x, w_off, b_off, w_deform, wbf, out);
}